// Round 4
// baseline (26492.993 us; speedup 1.0000x reference)
//
#include <hip/hip_runtime.h>
#include <hip/hip_bf16.h>

typedef __bf16 bf16x8 __attribute__((ext_vector_type(8)));
typedef float  f32x4  __attribute__((ext_vector_type(4)));
typedef float  f32x8  __attribute__((ext_vector_type(8)));
typedef int    i32x4  __attribute__((ext_vector_type(4)));

#define T_LEN 1024
#define DD    512
#define HH    512
#define NBLK  32     // 32 blocks x 16 h-cols = 512 = H  (round 4: half the rendezvous)
#define FSTRIDE 8    // flag spacing: 8 uints = 32 B

__device__ __forceinline__ f32x4 mfma16(bf16x8 a, bf16x8 b, f32x4 c) {
    return __builtin_amdgcn_mfma_f32_16x16x32_bf16(a, b, c, 0, 0, 0);
}
__device__ __forceinline__ float sigmf_(float v) { return 1.f / (1.f + __expf(-v)); }
__device__ __forceinline__ float tanhf_(float v) { return 1.f - 2.f / (1.f + __expf(2.f * v)); }
__device__ __forceinline__ bf16x8 cvt8(f32x8 v) {
    bf16x8 r;
    #pragma unroll
    for (int j = 0; j < 8; ++j) r[j] = (__bf16)v[j];
    return r;
}

// 16 coherent (sc1, LLC-served) 16-B fragment loads, ONE round-trip.
__device__ __forceinline__ void coh_load_frags(const unsigned short* p, i32x4 f[16]) {
    asm volatile(
        "global_load_dwordx4 %0, %16, off sc1\n\t"
        "global_load_dwordx4 %1, %16, off offset:64 sc1\n\t"
        "global_load_dwordx4 %2, %16, off offset:128 sc1\n\t"
        "global_load_dwordx4 %3, %16, off offset:192 sc1\n\t"
        "global_load_dwordx4 %4, %16, off offset:256 sc1\n\t"
        "global_load_dwordx4 %5, %16, off offset:320 sc1\n\t"
        "global_load_dwordx4 %6, %16, off offset:384 sc1\n\t"
        "global_load_dwordx4 %7, %16, off offset:448 sc1\n\t"
        "global_load_dwordx4 %8, %16, off offset:512 sc1\n\t"
        "global_load_dwordx4 %9, %16, off offset:576 sc1\n\t"
        "global_load_dwordx4 %10, %16, off offset:640 sc1\n\t"
        "global_load_dwordx4 %11, %16, off offset:704 sc1\n\t"
        "global_load_dwordx4 %12, %16, off offset:768 sc1\n\t"
        "global_load_dwordx4 %13, %16, off offset:832 sc1\n\t"
        "global_load_dwordx4 %14, %16, off offset:896 sc1\n\t"
        "global_load_dwordx4 %15, %16, off offset:960 sc1\n\t"
        "s_waitcnt vmcnt(0)"
        : "=&v"(f[0]), "=&v"(f[1]), "=&v"(f[2]), "=&v"(f[3]),
          "=&v"(f[4]), "=&v"(f[5]), "=&v"(f[6]), "=&v"(f[7]),
          "=&v"(f[8]), "=&v"(f[9]), "=&v"(f[10]), "=&v"(f[11]),
          "=&v"(f[12]), "=&v"(f[13]), "=&v"(f[14]), "=&v"(f[15])
        : "v"(p)
        : "memory");
}

// coherent f32x8 load (used once, at the t==T-1 stash fallback)
__device__ __forceinline__ f32x8 coh_load_f32x8(const float* p) {
    i32x4 a, b;
    asm volatile(
        "global_load_dwordx4 %0, %2, off sc1\n\t"
        "global_load_dwordx4 %1, %2, off offset:16 sc1\n\t"
        "s_waitcnt vmcnt(0)"
        : "=&v"(a), "=&v"(b) : "v"(p) : "memory");
    f32x8 r;
    #pragma unroll
    for (int j = 0; j < 4; ++j) { r[j] = __int_as_float(a[j]); r[4 + j] = __int_as_float(b[j]); }
    return r;
}

__device__ __forceinline__ void xpart_mfma(const float* xr, const bf16x8* wbh, const bf16x8* wbl,
                                           f32x4& ac0, f32x4& ac1, f32x4& ac2, f32x4& ac3) {
    #pragma unroll
    for (int kk = 0; kk < 16; ++kk) {
        bf16x8 av = cvt8(*(const f32x8*)(xr + kk * 32));
        if (kk & 1) { ac1 = mfma16(av, wbh[kk], ac1); ac3 = mfma16(av, wbl[kk], ac3); }
        else        { ac0 = mfma16(av, wbh[kk], ac0); ac2 = mfma16(av, wbl[kk], ac2); }
    }
}

// Round 10 = round 9 template, geometry 64x4waves -> 32x8waves.
//   Per-wave structure (weights, MFMA, stash addressing) is isomorphic; only
//   constants change: hc0 = blk*16, 4 n-tiles (wid>>1), gate map 32x16,
//   a_lds[32][68], poll set = 32 flags. Probes "rendezvous cost ~ participant
//   count" — sync graph (poll + 3 barriers + flag) unchanged.
__global__ void __launch_bounds__(512, 1)
lstm_pk(const float* __restrict__ x,    // (32,1024,512) fp32
        const float* __restrict__ h0,   // (32,512)
        const float* __restrict__ Wx,   // (512,2048)
        const float* __restrict__ Wh,   // (512,2048)
        const float* __restrict__ bias, // (2048)
        float* __restrict__ out,        // (32,1024,512) fp32
        unsigned* __restrict__ flags)   // 32 flags, 32-B spaced, zeroed
{
    __shared__ float a_lds[32][68];     // 64 B-cols + 4 pad

    const int tid  = threadIdx.x;
    const int blk  = blockIdx.x;
    const int hc0  = blk * 16;
    const int lane = tid & 63;
    const int wid  = tid >> 6;          // 8 waves: wid&1 = m-tile, wid>>1 = n-tile (0..3)
    const int q    = lane >> 4;
    const int mrow = (wid & 1) * 16 + (lane & 15);
    const int bcol = (wid >> 1) * 16 + (lane & 15);          // [0,64)
    const int gcol = (bcol >> 4) * HH + hc0 + (bcol & 15);   // gate = bcol/16, col in gate

    // ---- one-time: weight B-frags, bf16 hi+lo split (error ~2^-17) ----
    bf16x8 wbh[32], wbl[32];
    #pragma unroll
    for (int kk = 0; kk < 32; ++kk) {
        const float* wsrc = (kk < 16) ? Wx : Wh;
        const int kb = (kk & 15) * 32 + q * 8;
        bf16x8 wh_, wl_;
        #pragma unroll
        for (int j = 0; j < 8; ++j) {
            float w = wsrc[(size_t)(kb + j) * (4 * HH) + gcol];
            __bf16 hi = (__bf16)w;
            wh_[j] = hi;
            wl_[j] = (__bf16)(w - (float)hi);
        }
        wbh[kk] = wh_; wbl[kk] = wl_;
    }

    // ---- gate-thread mapping: thread <-> (n = tid>>4, hcol = hc0 + (tid&15)) ----
    const int gn  = tid >> 4;           // [0,32)
    const int glc = tid & 15;           // [0,16)
    const float bi  = bias[0 * HH + hc0 + glc];
    const float bf_ = bias[1 * HH + hc0 + glc];
    const float bo  = bias[2 * HH + hc0 + glc];
    const float bg  = bias[3 * HH + hc0 + glc];
    float creg = 0.f;
    const size_t outoff = (size_t)gn * T_LEN * HH + hc0 + glc;

    const float* xrow0 = x + (size_t)mrow * T_LEN * DD + q * 8;
    // stash addressing (bf16 packed in first half of a future out[.,tt,.] row)
    unsigned short* u16out = (unsigned short*)out;
    const unsigned short* cbase =
        (const unsigned short*)out + 2 * ((size_t)mrow * T_LEN * HH) + q * 8;
    const size_t stash_w = 2 * ((size_t)gn * T_LEN * HH) + (hc0 + glc);

    // prologue: x-part for t=0
    f32x4 ac0 = {0,0,0,0}, ac1 = {0,0,0,0}, ac2 = {0,0,0,0}, ac3 = {0,0,0,0};
    xpart_mfma(xrow0, wbh, wbl, ac0, ac1, ac2, ac3);

    #pragma unroll 1
    for (int t = 0; t < T_LEN; ++t) {
        // ---- barrier wait: all 32 flags >= t (t=0 passes immediately) ----
        if (wid == 0) {
            for (;;) {
                unsigned v = __hip_atomic_load(flags + (lane & 31) * FSTRIDE,
                                               __ATOMIC_RELAXED, __HIP_MEMORY_SCOPE_AGENT);
                if (__all((int)(v >= (unsigned)t))) break;
                __builtin_amdgcn_s_sleep(1);
            }
        }
        __syncthreads();

        // ---- h_{t-1} A-frags, straight from the bf16 stash (no LDS) ----
        bf16x8 hfrag[16];
        if (t == 0) {
            #pragma unroll
            for (int kk = 0; kk < 16; ++kk)
                hfrag[kk] = cvt8(*(const f32x8*)(h0 + (size_t)mrow * HH + kk * 32 + q * 8));
        } else if (t < T_LEN - 1) {
            i32x4 f[16];
            coh_load_frags(cbase + 2 * (size_t)(t + 1) * HH, f);   // stash of h_{t-1}
            #pragma unroll
            for (int kk = 0; kk < 16; ++kk) hfrag[kk] = *(bf16x8*)&f[kk];
        } else {   // t == T_LEN-1: stash for h_{T-2} was skipped; fp32 fallback
            #pragma unroll
            for (int kk = 0; kk < 16; ++kk)
                hfrag[kk] = cvt8(coh_load_f32x8(
                    out + (size_t)mrow * T_LEN * HH + (size_t)(t - 1) * HH + kk * 32 + q * 8));
        }

        // ---- h-part MFMAs (acc already holds x-part for this t) ----
        #pragma unroll
        for (int kk = 0; kk < 16; ++kk) {
            const int kw = 16 + kk;
            if (kw & 1) { ac1 = mfma16(hfrag[kk], wbh[kw], ac1); ac3 = mfma16(hfrag[kk], wbl[kw], ac3); }
            else        { ac0 = mfma16(hfrag[kk], wbh[kw], ac0); ac2 = mfma16(hfrag[kk], wbl[kw], ac2); }
        }

        // C/D layout [m89]: col = lane&15, row = quad*4 + reg (+ m-tile*16)
        f32x4 av4 = (ac0 + ac1) + (ac2 + ac3);
        #pragma unroll
        for (int r = 0; r < 4; ++r)
            a_lds[(wid & 1) * 16 + q * 4 + r][bcol] = av4[r];
        __syncthreads();

        // ---- gates (all 512 threads: 32 rows x 16 cols) ----
        float ai = a_lds[gn][glc]      + bi;
        float af = a_lds[gn][16 + glc] + bf_;
        float ao = a_lds[gn][32 + glc] + bo;
        float ag = a_lds[gn][48 + glc] + bg;
        float iv = sigmf_(ai), fv = sigmf_(af), ov = sigmf_(ao);
        float gv = tanhf_(ag);
        creg = fv * creg + iv * gv;
        float hv = ov * tanhf_(creg);

        // ---- intra-wave packing (tid^1 / tid^2 same wave; gn unaffected) ----
        unsigned hvu = __float_as_uint(hv);
        unsigned long long opair =
            ((unsigned long long)__shfl_xor(hvu, 1) << 32) | (unsigned long long)hvu;
        __bf16 hb = (__bf16)hv;
        unsigned hu = (unsigned)*(const unsigned short*)&hb;
        unsigned hp = (__shfl_xor(hu, 1) << 16) | hu;          // even glc: 2 cols
        unsigned long long hq =
            ((unsigned long long)__shfl_xor(hp, 2) << 32) | (unsigned long long)hp;

        const bool late = (t < T_LEN - 2);   // fp32 after flag except last 2 rows
        if (!late && (glc & 1) == 0)
            __hip_atomic_store((unsigned long long*)(out + outoff + (size_t)t * HH),
                               opair, __ATOMIC_RELAXED, __HIP_MEMORY_SCOPE_AGENT);
        if (t < T_LEN - 2 && (glc & 3) == 0)   // bf16 stash of h_t into out[:, t+2, :]
            __hip_atomic_store((unsigned long long*)(u16out + stash_w + 2 * (size_t)(t + 2) * HH),
                               hq, __ATOMIC_RELAXED, __HIP_MEMORY_SCOPE_AGENT);
        __syncthreads();                 // per-wave vmcnt(0): pre-flag stores at LLC

        // ---- arrive: own flag, own line, plain store (no RMW) ----
        if (tid == 0)
            __hip_atomic_store(flags + blk * FSTRIDE, (unsigned)(t + 1),
                               __ATOMIC_RELAXED, __HIP_MEMORY_SCOPE_AGENT);

        // ---- late fp32 out (off the pre-flag critical path) ----
        if (late && (glc & 1) == 0)
            __hip_atomic_store((unsigned long long*)(out + outoff + (size_t)t * HH),
                               opair, __ATOMIC_RELAXED, __HIP_MEMORY_SCOPE_AGENT);

        // ---- x-part for t+1, in the shadow of other blocks' drains/polls ----
        if (t + 1 < T_LEN) {
            ac0 = (f32x4){0,0,0,0}; ac1 = (f32x4){0,0,0,0};
            ac2 = (f32x4){0,0,0,0}; ac3 = (f32x4){0,0,0,0};
            xpart_mfma(xrow0 + (size_t)(t + 1) * DD, wbh, wbl, ac0, ac1, ac2, ac3);
        }
    }
}

extern "C" void kernel_launch(void* const* d_in, const int* in_sizes, int n_in,
                              void* d_out, int out_size, void* d_ws, size_t ws_size,
                              hipStream_t stream) {
    const float* x  = (const float*)d_in[0];
    const float* h0 = (const float*)d_in[1];
    const float* Wx = (const float*)d_in[2];
    const float* Wh = (const float*)d_in[3];
    const float* b  = (const float*)d_in[4];
    float* out = (float*)d_out;
    unsigned* flags = (unsigned*)d_ws;   // 1 KB of d_ws

    hipMemsetAsync(flags, 0, NBLK * FSTRIDE * sizeof(unsigned), stream);
    lstm_pk<<<dim3(NBLK), dim3(512), 0, stream>>>(x, h0, Wx, Wh, b, out, flags);
}

// Round 5
// 11563.335 us; speedup vs baseline: 2.2911x; 2.2911x over previous
//
#include <hip/hip_runtime.h>
#include <hip/hip_bf16.h>

typedef __bf16 bf16x8 __attribute__((ext_vector_type(8)));
typedef float  f32x4  __attribute__((ext_vector_type(4)));
typedef float  f32x8  __attribute__((ext_vector_type(8)));
typedef int    i32x4  __attribute__((ext_vector_type(4)));

#define T_LEN 1024
#define DD    512
#define HH    512
#define NBLK  64     // 64 blocks x 8 h-cols = 512 = H

__device__ __forceinline__ f32x4 mfma16(bf16x8 a, bf16x8 b, f32x4 c) {
    return __builtin_amdgcn_mfma_f32_16x16x32_bf16(a, b, c, 0, 0, 0);
}
__device__ __forceinline__ float sigmf_(float v) { return 1.f / (1.f + __expf(-v)); }
__device__ __forceinline__ float tanhf_(float v) { return 1.f - 2.f / (1.f + __expf(2.f * v)); }
__device__ __forceinline__ bf16x8 cvt8(f32x8 v) {
    bf16x8 r;
    #pragma unroll
    for (int j = 0; j < 8; ++j) r[j] = (__bf16)v[j];
    return r;
}

// 16 coherent (sc1, LLC-served) 16-B fragment loads, ONE round-trip.
__device__ __forceinline__ void coh_load_frags(const unsigned short* p, i32x4 f[16]) {
    asm volatile(
        "global_load_dwordx4 %0, %16, off sc1\n\t"
        "global_load_dwordx4 %1, %16, off offset:64 sc1\n\t"
        "global_load_dwordx4 %2, %16, off offset:128 sc1\n\t"
        "global_load_dwordx4 %3, %16, off offset:192 sc1\n\t"
        "global_load_dwordx4 %4, %16, off offset:256 sc1\n\t"
        "global_load_dwordx4 %5, %16, off offset:320 sc1\n\t"
        "global_load_dwordx4 %6, %16, off offset:384 sc1\n\t"
        "global_load_dwordx4 %7, %16, off offset:448 sc1\n\t"
        "global_load_dwordx4 %8, %16, off offset:512 sc1\n\t"
        "global_load_dwordx4 %9, %16, off offset:576 sc1\n\t"
        "global_load_dwordx4 %10, %16, off offset:640 sc1\n\t"
        "global_load_dwordx4 %11, %16, off offset:704 sc1\n\t"
        "global_load_dwordx4 %12, %16, off offset:768 sc1\n\t"
        "global_load_dwordx4 %13, %16, off offset:832 sc1\n\t"
        "global_load_dwordx4 %14, %16, off offset:896 sc1\n\t"
        "global_load_dwordx4 %15, %16, off offset:960 sc1\n\t"
        "s_waitcnt vmcnt(0)"
        : "=&v"(f[0]), "=&v"(f[1]), "=&v"(f[2]), "=&v"(f[3]),
          "=&v"(f[4]), "=&v"(f[5]), "=&v"(f[6]), "=&v"(f[7]),
          "=&v"(f[8]), "=&v"(f[9]), "=&v"(f[10]), "=&v"(f[11]),
          "=&v"(f[12]), "=&v"(f[13]), "=&v"(f[14]), "=&v"(f[15])
        : "v"(p)
        : "memory");
}

// Data-is-the-flag: re-load the 16 frags until every 8-B atomic-store unit is
// visibly nonzero (stash values have +0 remapped to 0x0001; region was zeroed
// at launch; 8-B stores are all-or-nothing, so one u16 per unit suffices).
__device__ __forceinline__ void poll_frags(const unsigned short* p, i32x4 f[16]) {
    for (;;) {
        coh_load_frags(p, f);
        unsigned mn = 0xffffffffu;
        #pragma unroll
        for (int kk = 0; kk < 16; ++kk) {
            mn = min(mn, (unsigned)f[kk][0] & 0xffffu);   // lo u16 of first 8-B unit
            mn = min(mn, (unsigned)f[kk][2] & 0xffffu);   // lo u16 of second 8-B unit
        }
        if (__all((int)(mn != 0u))) break;
        __builtin_amdgcn_s_sleep(1);
    }
}

__device__ __forceinline__ void xpart_mfma(const float* xr, const bf16x8* wbh, const bf16x8* wbl,
                                           f32x4& ac0, f32x4& ac1, f32x4& ac2, f32x4& ac3) {
    #pragma unroll
    for (int kk = 0; kk < 16; ++kk) {
        bf16x8 av = cvt8(*(const f32x8*)(xr + kk * 32));
        if (kk & 1) { ac1 = mfma16(av, wbh[kk], ac1); ac3 = mfma16(av, wbl[kk], ac3); }
        else        { ac0 = mfma16(av, wbh[kk], ac0); ac2 = mfma16(av, wbl[kk], ac2); }
    }
}

// Round 11: flagless persistent LSTM — blocks self-synchronize by polling the
// stash DATA (zero-initialized, written once, 8-B atomic, +0 remapped to a
// denormal). No flags, no drains, no rendezvous: 2 barriers/step, stores are
// fire-and-forget. Step T-2's stash goes to a zeroed d_ws arena (row T-2 in
// `out` is stash-contaminated, so its fp32 bytes can't be polled); step T-1
// polls the arena. Compute/geometry identical to the verified 64x256 template.
__global__ void __launch_bounds__(256, 1)
lstm_pk(const float* __restrict__ x,    // (32,1024,512) fp32
        const float* __restrict__ h0,   // (32,512)
        const float* __restrict__ Wx,   // (512,2048)
        const float* __restrict__ Wh,   // (512,2048)
        const float* __restrict__ bias, // (2048)
        float* __restrict__ out,        // (32,1024,512) fp32, zeroed at launch
        unsigned short* __restrict__ ws16)  // 32x512 bf16 arena, zeroed at launch
{
    __shared__ float a_lds[32][36];     // pitch 36: both access phases <=2-way (free)

    const int tid  = threadIdx.x;
    const int blk  = blockIdx.x;
    const int hc0  = blk * 8;
    const int lane = tid & 63;
    const int wid  = tid >> 6;          // 4 waves: wid&1 = m-tile, wid>>1 = n-tile
    const int q    = lane >> 4;
    const int mrow = (wid & 1) * 16 + (lane & 15);
    const int bcol = (wid >> 1) * 16 + (lane & 15);
    const int gcol = (bcol >> 3) * HH + hc0 + (bcol & 7);

    // ---- one-time: weight B-frags, bf16 hi+lo split (error ~2^-17) ----
    bf16x8 wbh[32], wbl[32];
    #pragma unroll
    for (int kk = 0; kk < 32; ++kk) {
        const float* wsrc = (kk < 16) ? Wx : Wh;
        const int kb = (kk & 15) * 32 + q * 8;
        bf16x8 wh_, wl_;
        #pragma unroll
        for (int j = 0; j < 8; ++j) {
            float w = wsrc[(size_t)(kb + j) * (4 * HH) + gcol];
            __bf16 hi = (__bf16)w;
            wh_[j] = hi;
            wl_[j] = (__bf16)(w - (float)hi);
        }
        wbh[kk] = wh_; wbl[kk] = wl_;
    }

    // ---- gate-thread mapping: thread <-> (n = tid>>3, hcol = hc0 + (tid&7)) ----
    const int gn  = tid >> 3;
    const int glc = tid & 7;
    const float bi  = bias[0 * HH + hc0 + glc];
    const float bf_ = bias[1 * HH + hc0 + glc];
    const float bo  = bias[2 * HH + hc0 + glc];
    const float bg  = bias[3 * HH + hc0 + glc];
    float creg = 0.f;
    const size_t outoff = (size_t)gn * T_LEN * HH + hc0 + glc;

    const float* xrow0 = x + (size_t)mrow * T_LEN * DD + q * 8;
    // stash addressing (bf16 packed in first half of a future out[.,tt,.] row)
    unsigned short* u16out = (unsigned short*)out;
    const unsigned short* cbase =
        (const unsigned short*)out + 2 * ((size_t)mrow * T_LEN * HH) + q * 8;
    const size_t stash_w = 2 * ((size_t)gn * T_LEN * HH) + (hc0 + glc);
    // d_ws arena: 32 rows x 512 cols bf16 (same frag stride 64 B as the stash)
    const unsigned short* wsrd = ws16 + (size_t)mrow * HH + q * 8;
    const size_t ws_w = (size_t)gn * HH + (hc0 + glc);

    // prologue: x-part for t=0
    f32x4 ac0 = {0,0,0,0}, ac1 = {0,0,0,0}, ac2 = {0,0,0,0}, ac3 = {0,0,0,0};
    xpart_mfma(xrow0, wbh, wbl, ac0, ac1, ac2, ac3);

    #pragma unroll 1
    for (int t = 0; t < T_LEN; ++t) {
        // ---- h_{t-1} A-frags: poll the data itself (no flags) ----
        bf16x8 hfrag[16];
        if (t == 0) {
            #pragma unroll
            for (int kk = 0; kk < 16; ++kk)
                hfrag[kk] = cvt8(*(const f32x8*)(h0 + (size_t)mrow * HH + kk * 32 + q * 8));
        } else {
            i32x4 f[16];
            if (t < T_LEN - 1)
                poll_frags(cbase + 2 * (size_t)(t + 1) * HH, f);   // stash of h_{t-1}
            else
                poll_frags(wsrd, f);                               // h_{T-2} from arena
            #pragma unroll
            for (int kk = 0; kk < 16; ++kk) hfrag[kk] = *(bf16x8*)&f[kk];
        }

        // ---- h-part MFMAs (acc already holds x-part for this t) ----
        #pragma unroll
        for (int kk = 0; kk < 16; ++kk) {
            const int kw = 16 + kk;
            if (kw & 1) { ac1 = mfma16(hfrag[kk], wbh[kw], ac1); ac3 = mfma16(hfrag[kk], wbl[kw], ac3); }
            else        { ac0 = mfma16(hfrag[kk], wbh[kw], ac0); ac2 = mfma16(hfrag[kk], wbl[kw], ac2); }
        }

        // C/D layout [m89]: col = lane&15, row = quad*4 + reg (+ m-tile*16)
        f32x4 av4 = (ac0 + ac1) + (ac2 + ac3);
        __syncthreads();                 // (1) gates(t-1) done reading a_lds
        #pragma unroll
        for (int r = 0; r < 4; ++r)
            a_lds[(wid & 1) * 16 + q * 4 + r][bcol] = av4[r];
        __syncthreads();                 // (2) a_lds(t) published

        // ---- gates ----
        float ai = a_lds[gn][glc]      + bi;
        float af = a_lds[gn][8 + glc]  + bf_;
        float ao = a_lds[gn][16 + glc] + bo;
        float ag = a_lds[gn][24 + glc] + bg;
        float iv = sigmf_(ai), fv = sigmf_(af), ov = sigmf_(ao);
        float gv = tanhf_(ag);
        creg = fv * creg + iv * gv;
        float hv = ov * tanhf_(creg);

        // ---- pack (intra-wave shuffles; glc = tid&7 so partners same wave) ----
        unsigned hvu = __float_as_uint(hv);
        unsigned long long opair =
            ((unsigned long long)__shfl_xor(hvu, 1) << 32) | (unsigned long long)hvu;
        __bf16 hb = (__bf16)hv;
        unsigned short hus = *(unsigned short*)&hb;
        if (hus == 0) hus = 1;           // +0 -> smallest denormal (poll sentinel)
        unsigned hu = (unsigned)hus;
        unsigned hp = (__shfl_xor(hu, 1) << 16) | hu;
        unsigned long long hq =
            ((unsigned long long)__shfl_xor(hp, 2) << 32) | (unsigned long long)hp;

        // ---- fire-and-forget stores (no drains, no flags) ----
        if ((glc & 1) == 0)
            __hip_atomic_store((unsigned long long*)(out + outoff + (size_t)t * HH),
                               opair, __ATOMIC_RELAXED, __HIP_MEMORY_SCOPE_AGENT);
        if ((glc & 3) == 0) {
            if (t < T_LEN - 2)           // stash h_t into out[:, t+2, :]
                __hip_atomic_store((unsigned long long*)(u16out + stash_w + 2 * (size_t)(t + 2) * HH),
                                   hq, __ATOMIC_RELAXED, __HIP_MEMORY_SCOPE_AGENT);
            else if (t == T_LEN - 2)     // stash h_{T-2} into the d_ws arena
                __hip_atomic_store((unsigned long long*)(ws16 + ws_w),
                                   hq, __ATOMIC_RELAXED, __HIP_MEMORY_SCOPE_AGENT);
        }

        // ---- x-part for t+1, overlapping other blocks' polls ----
        if (t + 1 < T_LEN) {
            ac0 = (f32x4){0,0,0,0}; ac1 = (f32x4){0,0,0,0};
            ac2 = (f32x4){0,0,0,0}; ac3 = (f32x4){0,0,0,0};
            xpart_mfma(xrow0 + (size_t)(t + 1) * DD, wbh, wbl, ac0, ac1, ac2, ac3);
        }
    }
}

extern "C" void kernel_launch(void* const* d_in, const int* in_sizes, int n_in,
                              void* d_out, int out_size, void* d_ws, size_t ws_size,
                              hipStream_t stream) {
    const float* x  = (const float*)d_in[0];
    const float* h0 = (const float*)d_in[1];
    const float* Wx = (const float*)d_in[2];
    const float* Wh = (const float*)d_in[3];
    const float* b  = (const float*)d_in[4];
    float* out = (float*)d_out;
    unsigned short* ws16 = (unsigned short*)d_ws;   // 32 KB arena

    // Self-contained zero-init: the data-poll scheme requires stash bytes = 0.
    // ~67 MB memset ≈ 15-25 us on-stream; graph-capture safe.
    hipMemsetAsync(out, 0, (size_t)32 * T_LEN * HH * sizeof(float), stream);
    hipMemsetAsync(ws16, 0, (size_t)32 * HH * sizeof(unsigned short), stream);
    lstm_pk<<<dim3(NBLK), dim3(256), 0, stream>>>(x, h0, Wx, Wh, b, out, ws16);
}